// Round 8
// baseline (194.632 us; speedup 1.0000x reference)
//
#include <hip/hip_runtime.h>
#include <hip/hip_bf16.h>

typedef __bf16 bf16;
typedef __bf16 bf16x2 __attribute__((ext_vector_type(2)));
typedef __bf16 bf16x4 __attribute__((ext_vector_type(4)));
typedef __bf16 bf16x8 __attribute__((ext_vector_type(8)));
typedef float f32x4 __attribute__((ext_vector_type(4)));

// (1/16) * log2(e): softmax scale folded into exp2
#define SM_C 0.09016994374947424f

typedef __attribute__((address_space(1))) const void as1_void;
typedef __attribute__((address_space(3))) void as3_void;

// ---------------------------------------------------------------------------
// prep: Wq/Wk/Wv/Wo [k][n] f32 -> Wt[mat][n][k] bf16. LDS-tiled 32x32
// transpose. grid 256 = 4 mats x 64 tiles.
// ---------------------------------------------------------------------------
__global__ __launch_bounds__(256) void transpose_w(
    const float* __restrict__ Wq, const float* __restrict__ Wk,
    const float* __restrict__ Wv, const float* __restrict__ Wo,
    bf16* __restrict__ Wt)
{
    __shared__ float T[32][33];
    const int bid = blockIdx.x;
    const int m = bid >> 6, tile = bid & 63;
    const int tn0 = (tile >> 3) * 32, tk0 = (tile & 7) * 32;
    const float* W = (m == 0) ? Wq : (m == 1) ? Wk : (m == 2) ? Wv : Wo;

    const int t = threadIdx.x;
    const int r = t >> 3, c4 = (t & 7) * 4;

    f32x4 v = *(const f32x4*)(W + (size_t)(tk0 + r) * 256 + tn0 + c4);
#pragma unroll
    for (int j = 0; j < 4; ++j) T[r][c4 + j] = v[j];
    __syncthreads();

    bf16x4 ov;
#pragma unroll
    for (int j = 0; j < 4; ++j) ov[j] = (bf16)T[c4 + j][r];
    *(bf16x4*)(Wt + (size_t)m * 65536 + (size_t)(tn0 + r) * 256 + tk0 + c4) = ov;
}

// ---------------------------------------------------------------------------
// Fused QKV as ONE GEMM: C[32768][768] = X[32768][256] x W[256][768].
// 1D grid 1536, 256 thr, 128x128 tile, BK=64, 36.9 KB LDS, 3 blk/CU.
// NEW: XCD-locality swizzle — the 6 bn-panels sharing an X row-tile are
// mapped co-XCD and temporally adjacent (xcd=wg&7, bm=(slot/6)*8+xcd,
// bn=slot%6; bijective), so X is HBM-fetched once and L2-hit 5x (before:
// sharers were ~256 blocks apart -> X re-read up to 6x).
// Q/K epilogue via LDS transit (R6); V epilogue packed 8B col-major stores.
// ---------------------------------------------------------------------------
__global__ __launch_bounds__(256, 3) void qkv_gemm(
    const float* __restrict__ X, const bf16* __restrict__ Wt,
    const float* __restrict__ bq, const float* __restrict__ bk,
    const float* __restrict__ bv,
    bf16* __restrict__ Qo, bf16* __restrict__ Ko, bf16* __restrict__ Vto)
{
    __shared__ __align__(16) char qsmem[36864];
    bf16* const Xs  = (bf16*)qsmem;            // [128][72]
    bf16* const Ws_ = (bf16*)(qsmem + 18432);  // [128][72]
    bf16* const Cs  = (bf16*)qsmem;            // epilogue: [128][132]

    const int t    = threadIdx.x;
    const int lane = t & 63, wv = t >> 6;
    const int quad = lane >> 4, l16 = lane & 15;

    const int wg   = blockIdx.x;          // 0..1535
    const int xcd  = wg & 7, slot = wg >> 3;
    const int bm   = (slot / 6) * 8 + xcd;
    const int bn   = slot % 6;
    const int proj = bn >> 1;

    const bf16* W = Wt + (size_t)proj * 65536 + (size_t)(bn & 1) * 32768;
    const float* bias = (proj == 0) ? bq : (proj == 1) ? bk : bv;

    const int m0 = t >> 3;
    const int c0 = (t & 7) * 8;

    const f32x4 zero = {0.0f, 0.0f, 0.0f, 0.0f};
    f32x4 acc[2][8];
#pragma unroll
    for (int i = 0; i < 2; ++i)
#pragma unroll
        for (int j = 0; j < 8; ++j) acc[i][j] = zero;

    f32x4 xa[4], xb[4]; bf16x8 wp[4];
#pragma unroll
    for (int p = 0; p < 4; ++p) {
        const float* px = X + (size_t)(bm * 128 + m0 + p * 32) * 256 + c0;
        xa[p] = *(const f32x4*)px; xb[p] = *(const f32x4*)(px + 4);
        wp[p] = *(const bf16x8*)(W + (size_t)(m0 + p * 32) * 256 + c0);
    }

    for (int kt = 0; kt < 4; ++kt) {
#pragma unroll
        for (int p = 0; p < 4; ++p) {
            bf16x8 r;
#pragma unroll
            for (int j = 0; j < 4; ++j) { r[j] = (bf16)xa[p][j]; r[j + 4] = (bf16)xb[p][j]; }
            *(bf16x8*)(Xs + (m0 + p * 32) * 72 + c0) = r;
            *(bf16x8*)(Ws_ + (m0 + p * 32) * 72 + c0) = wp[p];
        }
        __syncthreads();

        if (kt < 3) {
#pragma unroll
            for (int p = 0; p < 4; ++p) {
                const float* px = X + (size_t)(bm * 128 + m0 + p * 32) * 256 + (kt + 1) * 64 + c0;
                xa[p] = *(const f32x4*)px; xb[p] = *(const f32x4*)(px + 4);
                wp[p] = *(const bf16x8*)(W + (size_t)(m0 + p * 32) * 256 + (kt + 1) * 64 + c0);
            }
        }

#pragma unroll
        for (int ks = 0; ks < 2; ++ks) {
            bf16x8 a[2], bb[8];
#pragma unroll
            for (int mt = 0; mt < 2; ++mt)
                a[mt] = *(const bf16x8*)(Xs + (wv * 32 + mt * 16 + l16) * 72 + ks * 32 + quad * 8);
#pragma unroll
            for (int nt = 0; nt < 8; ++nt)
                bb[nt] = *(const bf16x8*)(Ws_ + (nt * 16 + l16) * 72 + ks * 32 + quad * 8);
#pragma unroll
            for (int mt = 0; mt < 2; ++mt)
#pragma unroll
                for (int nt = 0; nt < 8; ++nt)
                    acc[mt][nt] = __builtin_amdgcn_mfma_f32_16x16x32_bf16(
                        a[mt], bb[nt], acc[mt][nt], 0, 0, 0);
        }
        __syncthreads();
    }

    // epilogue
    if (proj == 2) {
#pragma unroll
        for (int nt = 0; nt < 8; ++nt) {
            int col = (bn & 1) * 128 + nt * 16 + l16;
            float bvv = bias[col];
#pragma unroll
            for (int mt = 0; mt < 2; ++mt) {
                int grow0 = bm * 128 + wv * 32 + mt * 16 + quad * 4;
                bf16x4 pk;
#pragma unroll
                for (int r = 0; r < 4; ++r) pk[r] = (bf16)(acc[mt][nt][r] + bvv);
                int b = grow0 >> 10, m = grow0 & 1023;
                *(bf16x4*)(Vto + (size_t)b * 262144 + (size_t)col * 1024 + m) = pk;
            }
        }
    } else {
        bf16* dst = (proj == 0) ? Qo : Ko;
#pragma unroll
        for (int nt = 0; nt < 8; ++nt) {
            float bvv = bias[(bn & 1) * 128 + nt * 16 + l16];
#pragma unroll
            for (int mt = 0; mt < 2; ++mt)
#pragma unroll
                for (int r = 0; r < 4; ++r)
                    Cs[(wv * 32 + mt * 16 + quad * 4 + r) * 132 + nt * 16 + l16] =
                        (bf16)(acc[mt][nt][r] + bvv);
        }
        __syncthreads();
#pragma unroll
        for (int i = 0; i < 8; ++i) {
            int chunk = i * 256 + t;
            int row = chunk >> 4, cc = chunk & 15;
            bf16x8 v = *(const bf16x8*)(Cs + row * 132 + cc * 8);
            *(bf16x8*)(dst + (size_t)(bm * 128 + row) * 256 + (bn & 1) * 128 + cc * 8) = v;
        }
    }
}

// ---------------------------------------------------------------------------
// Flash attention + fused O-projection (R5 structure, register-cap fixed).
// 512 thr / 8 waves, grid (32 b, 8 qt). Waves 0-3 (group 0) process even kv
// tiles, waves 4-7 odd; each wave owns 32 q-rows (mt=2) -> every LDS
// B-fragment feeds 2 MFMAs, each group stages/reads only its kv-parity:
// per-tile LDS frag traffic HALVES vs the 16-row design.
// __launch_bounds__(512, 1): R5/R7 failed because min-waves=2 capped the
// allocator at 128 arch VGPRs -> spill (R5: +20 MB writes). This design
// needs ~260 regs; LDS (152 KB) already forces 1 block/CU, so freeing the
// allocator costs no occupancy (still 2 waves/SIMD).
// K staged via global_load_lds (pre-swizzled source, XOR reads); V via
// registers; swapped QK^T -> packed bf16x2 P writes. One barrier/iter.
// Group merge in f32 via LDS scratch, then fused O-projection.
// LDS map (bytes, total 155648):
//   loop:  G0 Ks@0[2][16384] Vs@32768[2][20480]; G1 Ks@73728 Vs@106496;
//          P@147456 (8 x 1024)
//   epi:   Os@0 [128][264]b16; scr@67584 f32[128][132]; lstS@135168;
//          Wos@67584 (after merge)
// ---------------------------------------------------------------------------
__global__ __launch_bounds__(512, 1) void flash_attn(
    const bf16* __restrict__ Qr, const bf16* __restrict__ K,
    const bf16* __restrict__ Vt, const bf16* __restrict__ Wo,
    const float* __restrict__ bo, float* __restrict__ out)
{
    __shared__ __align__(16) char smem[155648];

    const int t    = threadIdx.x;
    const int lane = t & 63, wv = t >> 6;
    const int quad = lane >> 4, l16 = lane & 15;
    const int g    = wv >> 2, wl = wv & 3;       // kv-group, wave-in-group
    const int gt   = t & 255;                    // group-local thread id
    const int b  = blockIdx.x;   // 0..31 (fastest -> XCD = b % 8)
    const int qt = blockIdx.y;   // 0..7

    char* const KsB = smem + g * 73728;            // [2][32][512B]
    char* const VsB = smem + g * 73728 + 32768;    // [2][256][80B]
    char* const Pb  = smem + 147456 + wv * 1024;   // [16][64B] swizzled
    const int psw = (l16 & 7) << 4;

    // Q fragments (B operand of swapped QK^T)
    bf16x8 qf[2][8];
#pragma unroll
    for (int mt = 0; mt < 2; ++mt) {
        const bf16* qp = Qr + ((size_t)b * 1024 + qt * 128 + wl * 32 + mt * 16 + l16) * 256 + quad * 8;
#pragma unroll
        for (int ks = 0; ks < 8; ++ks)
            qf[mt][ks] = *(const bf16x8*)(qp + ks * 32);
    }

    const f32x4 zero = {0.0f, 0.0f, 0.0f, 0.0f};
    f32x4 o[2][16];
#pragma unroll
    for (int mt = 0; mt < 2; ++mt)
#pragma unroll
        for (int n = 0; n < 16; ++n) o[mt][n] = zero;
    float lst[2] = {0.f, 0.f};

    // V staging split: 256 thr/group, 4 x 16B each
    const int vc  = gt >> 1;          // channel 0..127 (+128 for p>=2)
    const int vk8 = (gt & 1) * 8;     // kv 0/8 (+16 for odd p)
    bf16x8 vp[4];

    // K tile T -> LDS buffer buf, direct global->LDS, source pre-swizzled
    auto gloadK = [&](int T, int buf) {
#pragma unroll
        for (int p = 0; p < 4; ++p) {
            int chunk = wl * 4 + p;                 // 16 x 1KB chunks
            int row   = chunk * 2 + (lane >> 5);
            int w16   = (lane & 31) ^ (row & 7);    // pre-swizzled 16B slot
            const bf16* gsrc = K + ((size_t)b * 1024 + T * 32 + row) * 256 + w16 * 8;
            __builtin_amdgcn_global_load_lds((as1_void*)gsrc,
                (as3_void*)(KsB + buf * 16384 + chunk * 1024), 16, 0, 0);
        }
    };
    auto vload = [&](int T) {
#pragma unroll
        for (int p = 0; p < 4; ++p) {
            int c = vc + 128 * (p >> 1), k8 = vk8 + (p & 1) * 16;
            vp[p] = *(const bf16x8*)(Vt + (size_t)b * 262144 + (size_t)c * 1024 + T * 32 + k8);
        }
    };
    auto vcommit = [&](int buf) {
#pragma unroll
        for (int p = 0; p < 4; ++p) {
            int c = vc + 128 * (p >> 1), k8 = vk8 + (p & 1) * 16;
            *(bf16x8*)(VsB + buf * 20480 + c * 80 + k8 * 2) = vp[p];
        }
    };

    // prologue: tile g -> buf0; V tile g+2 loads in flight
    gloadK(g, 0);
    vload(g); vcommit(0); vload(g + 2);

    for (int i = 0; i < 16; ++i) {
        const int buf = i & 1;
        __syncthreads();   // drains K gloads + V commits of tile for iter i

        if (i < 15) {
            gloadK(g + 2 * (i + 1), buf ^ 1);
            vcommit(buf ^ 1);              // vp holds tile g+2(i+1)
            if (i < 14) vload(g + 2 * (i + 2));
        }

        // ---- swapped S = K Q^T: C row = kv (quad*4+r), col = q (l16)
        f32x4 s[2][2];
        s[0][0] = zero; s[0][1] = zero; s[1][0] = zero; s[1][1] = zero;
        const char* Kbuf = KsB + buf * 16384;
#pragma unroll
        for (int ks = 0; ks < 8; ++ks) {
#pragma unroll
            for (int n = 0; n < 2; ++n) {
                bf16x8 kb = *(const bf16x8*)(Kbuf + (n * 16 + l16) * 512 + ((ks * 64 + quad * 16) ^ psw));
                s[0][n] = __builtin_amdgcn_mfma_f32_16x16x32_bf16(kb, qf[0][ks], s[0][n], 0, 0, 0);
                s[1][n] = __builtin_amdgcn_mfma_f32_16x16x32_bf16(kb, qf[1][ks], s[1][n], 0, 0, 0);
            }
        }

        // ---- softmax + packed P (kv-consecutive pairs) + A-frag read
        bf16x8 af[2];
#pragma unroll
        for (int mt = 0; mt < 2; ++mt) {
#pragma unroll
            for (int n = 0; n < 2; ++n) {
#pragma unroll
                for (int h = 0; h < 2; ++h) {
                    float p0 = __builtin_amdgcn_exp2f(s[mt][n][2 * h] * SM_C);
                    float p1 = __builtin_amdgcn_exp2f(s[mt][n][2 * h + 1] * SM_C);
                    lst[mt] += p0 + p1;
                    bf16x2 pk; pk[0] = (bf16)p0; pk[1] = (bf16)p1;
                    *(bf16x2*)(Pb + ((l16 * 64 + n * 32 + quad * 8 + h * 4) ^ psw)) = pk;
                }
            }
            af[mt] = *(const bf16x8*)(Pb + ((l16 * 64 + quad * 16) ^ psw));
        }

        // ---- O += P V
        const char* Vbuf = VsB + buf * 20480;
#pragma unroll
        for (int n = 0; n < 16; ++n) {
            bf16x8 vb = *(const bf16x8*)(Vbuf + (n * 16 + l16) * 80 + quad * 16);
            o[0][n] = __builtin_amdgcn_mfma_f32_16x16x32_bf16(af[0], vb, o[0][n], 0, 0, 0);
            o[1][n] = __builtin_amdgcn_mfma_f32_16x16x32_bf16(af[1], vb, o[1][n], 0, 0, 0);
        }
    }

    __syncthreads();   // end of loop: all LDS regions dead

    // ---- quad-reduce l (lane then holds full group-partial for q=mt*16+l16)
#pragma unroll
    for (int mt = 0; mt < 2; ++mt) {
        lst[mt] += __shfl_xor(lst[mt], 16, 64);
        lst[mt] += __shfl_xor(lst[mt], 32, 64);
    }

    float* const scr  = (float*)(smem + 67584);    // [col 128][132] f32
    float* const lstS = (float*)(smem + 135168);   // [128]
    bf16*  const Os   = (bf16*)smem;               // [128][264]

    // ---- group merge, phase A (cols 0..127)
    if (g == 1) {
        if (quad == 0) {
            lstS[wl * 32 + l16]      = lst[0];
            lstS[wl * 32 + 16 + l16] = lst[1];
        }
#pragma unroll
        for (int mt = 0; mt < 2; ++mt)
#pragma unroll
            for (int n = 0; n < 8; ++n)
                *(f32x4*)(scr + (size_t)(n * 16 + l16) * 132 + wl * 32 + mt * 16 + quad * 4) = o[mt][n];
    }
    __syncthreads();
    if (g == 0) {
        lst[0] += lstS[wl * 32 + l16];
        lst[1] += lstS[wl * 32 + 16 + l16];
#pragma unroll
        for (int mt = 0; mt < 2; ++mt)
#pragma unroll
            for (int n = 0; n < 8; ++n) {
                f32x4 m = *(const f32x4*)(scr + (size_t)(n * 16 + l16) * 132 + wl * 32 + mt * 16 + quad * 4);
                o[mt][n] += m;
            }
    }
    __syncthreads();
    // ---- phase B (cols 128..255)
    if (g == 1) {
#pragma unroll
        for (int mt = 0; mt < 2; ++mt)
#pragma unroll
            for (int n = 8; n < 16; ++n)
                *(f32x4*)(scr + (size_t)((n - 8) * 16 + l16) * 132 + wl * 32 + mt * 16 + quad * 4) = o[mt][n];
    }
    __syncthreads();
    if (g == 0) {
#pragma unroll
        for (int mt = 0; mt < 2; ++mt)
#pragma unroll
            for (int n = 8; n < 16; ++n) {
                f32x4 m = *(const f32x4*)(scr + (size_t)((n - 8) * 16 + l16) * 132 + wl * 32 + mt * 16 + quad * 4);
                o[mt][n] += m;
            }
        // ---- normalize, write merged attended tile (bf16, [128][264])
        float inv[2][4];
#pragma unroll
        for (int mt = 0; mt < 2; ++mt)
#pragma unroll
            for (int r = 0; r < 4; ++r)
                inv[mt][r] = 1.0f / __shfl(lst[mt], quad * 4 + r, 64);
#pragma unroll
        for (int mt = 0; mt < 2; ++mt)
#pragma unroll
            for (int n = 0; n < 16; ++n)
#pragma unroll
                for (int r = 0; r < 4; ++r)
                    Os[(size_t)(wl * 32 + mt * 16 + quad * 4 + r) * 264 + n * 16 + l16] =
                        (bf16)(o[mt][n][r] * inv[mt][r]);
    }
    __syncthreads();   // Os visible to all; scr reads done before Wos overwrite

    // ---- fused O-projection: out[128][256] = Os x Wo^T(+bo), two col-halves
    bf16* const Wos = (bf16*)(smem + 67584);
    const int rh = (wv & 1) * 64;      // wave's row strip
    const int nq = wv >> 1;            // wave's 32-col strip within half
    const size_t orow0 = (size_t)b * 1024 + qt * 128 + rh;

#pragma unroll
    for (int h = 0; h < 2; ++h) {
        if (h) __syncthreads();        // previous half's Wos reads done
#pragma unroll
        for (int i = 0; i < 8; ++i) {
            int c = t + i * 512;
            int row = c >> 5, c8 = (c & 31) * 8;
            *(bf16x8*)(Wos + row * 264 + c8) =
                *(const bf16x8*)(Wo + (size_t)(h * 128 + row) * 256 + c8);
        }
        __syncthreads();

        f32x4 acc[4][2];
#pragma unroll
        for (int mt = 0; mt < 4; ++mt) { acc[mt][0] = zero; acc[mt][1] = zero; }

#pragma unroll
        for (int ks = 0; ks < 8; ++ks) {
            bf16x8 a[4], bb[2];
#pragma unroll
            for (int mt = 0; mt < 4; ++mt)
                a[mt] = *(const bf16x8*)(Os + (size_t)(rh + mt * 16 + l16) * 264 + ks * 32 + quad * 8);
#pragma unroll
            for (int nt = 0; nt < 2; ++nt)
                bb[nt] = *(const bf16x8*)(Wos + (nq * 32 + nt * 16 + l16) * 264 + ks * 32 + quad * 8);
#pragma unroll
            for (int mt = 0; mt < 4; ++mt)
#pragma unroll
                for (int nt = 0; nt < 2; ++nt)
                    acc[mt][nt] = __builtin_amdgcn_mfma_f32_16x16x32_bf16(
                        a[mt], bb[nt], acc[mt][nt], 0, 0, 0);
        }

#pragma unroll
        for (int nt = 0; nt < 2; ++nt) {
            int col = h * 128 + nq * 32 + nt * 16 + l16;
            float bvv = bo[col];
#pragma unroll
            for (int mt = 0; mt < 4; ++mt) {
#pragma unroll
                for (int r = 0; r < 4; ++r) {
                    size_t row = orow0 + mt * 16 + quad * 4 + r;
                    out[row * 256 + col] = acc[mt][nt][r] + bvv;
                }
            }
        }
    }
}

// ---------------------------------------------------------------------------
extern "C" void kernel_launch(void* const* d_in, const int* in_sizes, int n_in,
                              void* d_out, int out_size, void* d_ws, size_t ws_size,
                              hipStream_t stream)
{
    (void)in_sizes; (void)n_in; (void)out_size; (void)ws_size;
    const float* X  = (const float*)d_in[0];
    const float* Wq = (const float*)d_in[1];
    const float* bq = (const float*)d_in[2];
    const float* Wk = (const float*)d_in[3];
    const float* bk = (const float*)d_in[4];
    const float* Wv = (const float*)d_in[5];
    const float* bv = (const float*)d_in[6];
    const float* Wo = (const float*)d_in[7];
    const float* bo = (const float*)d_in[8];
    float* out = (float*)d_out;

    const size_t NTOK = (size_t)32768 * 256;

    // workspace: Wt (4 mats = 512 KB) + Q + K + Vt
    bf16* Wt  = (bf16*)d_ws;
    bf16* Qw  = (bf16*)d_ws + 262144;
    bf16* Kw  = Qw + NTOK;
    bf16* Vtw = Kw + NTOK;

    transpose_w<<<256, 256, 0, stream>>>(Wq, Wk, Wv, Wo, Wt);
    qkv_gemm   <<<1536, 256, 0, stream>>>(X, Wt, bq, bk, bv, Qw, Kw, Vtw);
    flash_attn <<<dim3(32, 8), 512, 0, stream>>>(Qw, Kw, Vtw, Wt + 3 * 65536, bo, out);
}

// Round 9
// 185.807 us; speedup vs baseline: 1.0475x; 1.0475x over previous
//
#include <hip/hip_runtime.h>
#include <hip/hip_bf16.h>

typedef __bf16 bf16;
typedef __bf16 bf16x2 __attribute__((ext_vector_type(2)));
typedef __bf16 bf16x4 __attribute__((ext_vector_type(4)));
typedef __bf16 bf16x8 __attribute__((ext_vector_type(8)));
typedef float f32x4 __attribute__((ext_vector_type(4)));
typedef float f32x16 __attribute__((ext_vector_type(16)));
typedef unsigned int u32;

// (1/16) * log2(e): softmax scale folded into exp2
#define SM_C 0.09016994374947424f

typedef __attribute__((address_space(1))) const void as1_void;
typedef __attribute__((address_space(3))) void as3_void;

// ---------------------------------------------------------------------------
// prep: Wq/Wk/Wv/Wo [k][n] f32 -> Wt[mat][n][k] bf16. LDS-tiled 32x32
// transpose. grid 256 = 4 mats x 64 tiles.
// ---------------------------------------------------------------------------
__global__ __launch_bounds__(256) void transpose_w(
    const float* __restrict__ Wq, const float* __restrict__ Wk,
    const float* __restrict__ Wv, const float* __restrict__ Wo,
    bf16* __restrict__ Wt)
{
    __shared__ float T[32][33];
    const int bid = blockIdx.x;
    const int m = bid >> 6, tile = bid & 63;
    const int tn0 = (tile >> 3) * 32, tk0 = (tile & 7) * 32;
    const float* W = (m == 0) ? Wq : (m == 1) ? Wk : (m == 2) ? Wv : Wo;

    const int t = threadIdx.x;
    const int r = t >> 3, c4 = (t & 7) * 4;

    f32x4 v = *(const f32x4*)(W + (size_t)(tk0 + r) * 256 + tn0 + c4);
#pragma unroll
    for (int j = 0; j < 4; ++j) T[r][c4 + j] = v[j];
    __syncthreads();

    bf16x4 ov;
#pragma unroll
    for (int j = 0; j < 4; ++j) ov[j] = (bf16)T[c4 + j][r];
    *(bf16x4*)(Wt + (size_t)m * 65536 + (size_t)(tn0 + r) * 256 + tk0 + c4) = ov;
}

// ---------------------------------------------------------------------------
// Fused QKV as ONE GEMM (round-6 version, verbatim — best measured).
// grid (256 bm, 6 bn), 256 thr, 128x128 tile, BK=64, 36.9 KB LDS, 3 blk/CU.
// Q/K epilogue via LDS transit; V epilogue packed 8B col-major stores.
// ---------------------------------------------------------------------------
__global__ __launch_bounds__(256, 3) void qkv_gemm(
    const float* __restrict__ X, const bf16* __restrict__ Wt,
    const float* __restrict__ bq, const float* __restrict__ bk,
    const float* __restrict__ bv,
    bf16* __restrict__ Qo, bf16* __restrict__ Ko, bf16* __restrict__ Vto)
{
    __shared__ __align__(16) char qsmem[36864];
    bf16* const Xs  = (bf16*)qsmem;            // [128][72]
    bf16* const Ws_ = (bf16*)(qsmem + 18432);  // [128][72]
    bf16* const Cs  = (bf16*)qsmem;            // epilogue: [128][132]

    const int t    = threadIdx.x;
    const int lane = t & 63, wv = t >> 6;
    const int quad = lane >> 4, l16 = lane & 15;
    const int bm   = blockIdx.x;
    const int bn   = blockIdx.y;
    const int proj = bn >> 1;

    const bf16* W = Wt + (size_t)proj * 65536 + (size_t)(bn & 1) * 32768;
    const float* bias = (proj == 0) ? bq : (proj == 1) ? bk : bv;

    const int m0 = t >> 3;
    const int c0 = (t & 7) * 8;

    const f32x4 zero = {0.0f, 0.0f, 0.0f, 0.0f};
    f32x4 acc[2][8];
#pragma unroll
    for (int i = 0; i < 2; ++i)
#pragma unroll
        for (int j = 0; j < 8; ++j) acc[i][j] = zero;

    f32x4 xa[4], xb[4]; bf16x8 wp[4];
#pragma unroll
    for (int p = 0; p < 4; ++p) {
        const float* px = X + (size_t)(bm * 128 + m0 + p * 32) * 256 + c0;
        xa[p] = *(const f32x4*)px; xb[p] = *(const f32x4*)(px + 4);
        wp[p] = *(const bf16x8*)(W + (size_t)(m0 + p * 32) * 256 + c0);
    }

    for (int kt = 0; kt < 4; ++kt) {
#pragma unroll
        for (int p = 0; p < 4; ++p) {
            bf16x8 r;
#pragma unroll
            for (int j = 0; j < 4; ++j) { r[j] = (bf16)xa[p][j]; r[j + 4] = (bf16)xb[p][j]; }
            *(bf16x8*)(Xs + (m0 + p * 32) * 72 + c0) = r;
            *(bf16x8*)(Ws_ + (m0 + p * 32) * 72 + c0) = wp[p];
        }
        __syncthreads();

        if (kt < 3) {
#pragma unroll
            for (int p = 0; p < 4; ++p) {
                const float* px = X + (size_t)(bm * 128 + m0 + p * 32) * 256 + (kt + 1) * 64 + c0;
                xa[p] = *(const f32x4*)px; xb[p] = *(const f32x4*)(px + 4);
                wp[p] = *(const bf16x8*)(W + (size_t)(m0 + p * 32) * 256 + (kt + 1) * 64 + c0);
            }
        }

#pragma unroll
        for (int ks = 0; ks < 2; ++ks) {
            bf16x8 a[2], bb[8];
#pragma unroll
            for (int mt = 0; mt < 2; ++mt)
                a[mt] = *(const bf16x8*)(Xs + (wv * 32 + mt * 16 + l16) * 72 + ks * 32 + quad * 8);
#pragma unroll
            for (int nt = 0; nt < 8; ++nt)
                bb[nt] = *(const bf16x8*)(Ws_ + (nt * 16 + l16) * 72 + ks * 32 + quad * 8);
#pragma unroll
            for (int mt = 0; mt < 2; ++mt)
#pragma unroll
                for (int nt = 0; nt < 8; ++nt)
                    acc[mt][nt] = __builtin_amdgcn_mfma_f32_16x16x32_bf16(
                        a[mt], bb[nt], acc[mt][nt], 0, 0, 0);
        }
        __syncthreads();
    }

    // epilogue
    if (proj == 2) {
#pragma unroll
        for (int nt = 0; nt < 8; ++nt) {
            int col = (bn & 1) * 128 + nt * 16 + l16;
            float bvv = bias[col];
#pragma unroll
            for (int mt = 0; mt < 2; ++mt) {
                int grow0 = bm * 128 + wv * 32 + mt * 16 + quad * 4;
                bf16x4 pk;
#pragma unroll
                for (int r = 0; r < 4; ++r) pk[r] = (bf16)(acc[mt][nt][r] + bvv);
                int b = grow0 >> 10, m = grow0 & 1023;
                *(bf16x4*)(Vto + (size_t)b * 262144 + (size_t)col * 1024 + m) = pk;
            }
        }
    } else {
        bf16* dst = (proj == 0) ? Qo : Ko;
#pragma unroll
        for (int nt = 0; nt < 8; ++nt) {
            float bvv = bias[(bn & 1) * 128 + nt * 16 + l16];
#pragma unroll
            for (int mt = 0; mt < 2; ++mt)
#pragma unroll
                for (int r = 0; r < 4; ++r)
                    Cs[(wv * 32 + mt * 16 + quad * 4 + r) * 132 + nt * 16 + l16] =
                        (bf16)(acc[mt][nt][r] + bvv);
        }
        __syncthreads();
#pragma unroll
        for (int i = 0; i < 8; ++i) {
            int chunk = i * 256 + t;
            int row = chunk >> 4, cc = chunk & 15;
            bf16x8 v = *(const bf16x8*)(Cs + row * 132 + cc * 8);
            *(bf16x8*)(dst + (size_t)(bm * 128 + row) * 256 + (bn & 1) * 128 + cc * 8) = v;
        }
    }
}

// ---------------------------------------------------------------------------
// Flash attention + fused O-projection, v4: 32x32x16 MFMA.
// 512 thr / 8 waves, grid (32 b, 8 qt). Wave = (qg = wv&3: 32 q-rows,
// cg = wv>>2: 128-ch half). 32x32 shape halves LDS operand bytes per MAC
// (1 KB per 16384 MACs); P stays fully IN REGISTERS via swapped QK^T
// (A=K, B=Q -> lane owns one q-column) + 4x shfl_xor(32) half-exchange.
// Register budget ~190 < the 256-unified cap a 512-thr block imposes
// (R5/R8 post-mortem: pool = 512 regs/SIMD, 8-wave block = 2 waves/SIMD).
// K/V/Wo staged via global_load_lds, both-sides XOR swizzle (R5-verified
// pattern); all frag reads bank-optimal (8 dwords/bank per b128, derived).
// One barrier per KV tile; prefetch issued right after it.
// LDS (98304 B): loop Ks[2][16K]@0, Vs[2][16K]@32768;
//                epi  Os[128][512B swz]@0, Wos[64][512B swz]@65536.
// ---------------------------------------------------------------------------
__global__ __launch_bounds__(512, 2) void flash_attn(
    const bf16* __restrict__ Qr, const bf16* __restrict__ K,
    const bf16* __restrict__ Vt, const bf16* __restrict__ Wo,
    const float* __restrict__ bo, float* __restrict__ out)
{
    __shared__ __align__(16) char smem[98304];

    const int t    = threadIdx.x;
    const int lane = t & 63, wv = t >> 6;
    const int l32  = lane & 31, hi = lane >> 5;
    const int qg   = wv & 3, cg = wv >> 2;
    const int b  = blockIdx.x;   // 0..31 (fastest -> XCD = b % 8)
    const int qt = blockIdx.y;   // 0..7

    // Q B-frags (swapped QK^T): B[row=q=l32][k=ks*16+hi*8+j]
    bf16x8 qf[16];
    {
        const bf16* qp = Qr + ((size_t)b * 1024 + qt * 128 + qg * 32 + l32) * 256 + hi * 8;
#pragma unroll
        for (int ks = 0; ks < 16; ++ks)
            qf[ks] = *(const bf16x8*)(qp + ks * 16);
    }

    f32x16 o[4];   // ch tiles n: 32q x 32ch, chbase = cg*128 + n*32
#pragma unroll
    for (int n = 0; n < 4; ++n)
#pragma unroll
        for (int i = 0; i < 16; ++i) o[n][i] = 0.0f;
    float lst = 0.f;

    // K tile -> LDS [32 kv][32 x 16B slots], slot image: lds[kv][sp] = K[kv][sp ^ (kv&7)]
    auto gloadK = [&](int T, int buf) {
#pragma unroll
        for (int p = 0; p < 2; ++p) {
            int chunk = wv * 2 + p;                 // 16 x 1KB chunks
            int S = chunk * 64 + lane;              // linear 16B slot 0..1023
            int kv = S >> 5, sp = S & 31;
            int ss = sp ^ (kv & 7);
            const bf16* g = K + ((size_t)b * 1024 + T * 32 + kv) * 256 + ss * 8;
            __builtin_amdgcn_global_load_lds((as1_void*)g,
                (as3_void*)(smem + buf * 16384 + chunk * 1024), 16, 0, 0);
        }
    };
    // V tile -> LDS [256 ch][4 x 16B slots], lds[ch][sp] = Vt[ch][(sp ^ (ch&3))*8 kv]
    auto gloadV = [&](int T, int buf) {
#pragma unroll
        for (int p = 0; p < 2; ++p) {
            int chunk = wv * 2 + p;
            int S = chunk * 64 + lane;
            int ch = S >> 2, sp = S & 3;
            int ss = sp ^ (ch & 3);
            const bf16* g = Vt + (size_t)b * 262144 + (size_t)ch * 1024 + T * 32 + ss * 8;
            __builtin_amdgcn_global_load_lds((as1_void*)g,
                (as3_void*)(smem + 32768 + buf * 16384 + chunk * 1024), 16, 0, 0);
        }
    };

    gloadK(0, 0); gloadV(0, 0);

    for (int j = 0; j < 32; ++j) {
        const int buf = j & 1;
        __syncthreads();   // drains tile-j gloads (issued last iter); buf^1 reads done

        if (j < 31) { gloadK(j + 1, buf ^ 1); gloadV(j + 1, buf ^ 1); }

        // ---- S = K Q^T (D[row=kv][col=q]); A-frag: kv=l32, k=ks*16+hi*8
        f32x16 s;
#pragma unroll
        for (int i = 0; i < 16; ++i) s[i] = 0.0f;
        const char* Kb = smem + buf * 16384;
#pragma unroll
        for (int ks = 0; ks < 16; ++ks) {
            int ss = (ks * 2 + hi) ^ (l32 & 7);
            bf16x8 kb = *(const bf16x8*)(Kb + l32 * 512 + ss * 16);
            s = __builtin_amdgcn_mfma_f32_32x32x16_bf16(kb, qf[ks], s, 0, 0, 0);
        }

        // ---- softmax (lane owns q=qg*32+l32; regs r -> kv=(r&3)+8*(r>>2)+4*hi)
        float p[16];
#pragma unroll
        for (int r = 0; r < 16; ++r) { p[r] = __builtin_amdgcn_exp2f(s[r] * SM_C); lst += p[r]; }

        // pack bf16 pairs: w0,w1=A(kv 4hi+0..3) w2,w3=B(8+4hi..) w4,w5=C(16+..) w6,w7=D(24+..)
        u32 w[8];
#pragma unroll
        for (int i = 0; i < 8; ++i) {
            bf16x2 v2; v2[0] = (bf16)p[2 * i]; v2[1] = (bf16)p[2 * i + 1];
            w[i] = __builtin_bit_cast(u32, v2);
        }
        // half-exchange: PV A-frag needs k=kv=hi*8+j (+16 for half 1)
        u32 s0 = hi ? w[0] : w[2];
        u32 s1 = hi ? w[1] : w[3];
        u32 r0 = (u32)__shfl_xor((int)s0, 32, 64);
        u32 r1 = (u32)__shfl_xor((int)s1, 32, 64);
        u32 s2 = hi ? w[4] : w[6];
        u32 s3 = hi ? w[5] : w[7];
        u32 r2 = (u32)__shfl_xor((int)s2, 32, 64);
        u32 r3 = (u32)__shfl_xor((int)s3, 32, 64);
        u32 f0[4], f1[4];
        f0[0] = hi ? r0 : w[0];  f0[1] = hi ? r1 : w[1];
        f0[2] = hi ? w[2] : r0;  f0[3] = hi ? w[3] : r1;
        f1[0] = hi ? r2 : w[4];  f1[1] = hi ? r3 : w[5];
        f1[2] = hi ? w[6] : r2;  f1[3] = hi ? w[7] : r3;
        bf16x8 pa0, pa1;
        __builtin_memcpy(&pa0, f0, 16);
        __builtin_memcpy(&pa1, f1, 16);

        // ---- O += P V  (B-frag: ch=chb, k=kv=h*16+hi*8+j; slot (h*2+hi)^(chb&3))
        const char* Vb = smem + 32768 + buf * 16384;
#pragma unroll
        for (int n = 0; n < 4; ++n) {
            int chb = cg * 128 + n * 32 + l32;
            const char* vrow = Vb + chb * 64;
            bf16x8 v0 = *(const bf16x8*)(vrow + ((hi ^ (chb & 3)) << 4));
            bf16x8 v1 = *(const bf16x8*)(vrow + (((2 + hi) ^ (chb & 3)) << 4));
            o[n] = __builtin_amdgcn_mfma_f32_32x32x16_bf16(pa0, v0, o[n], 0, 0, 0);
            o[n] = __builtin_amdgcn_mfma_f32_32x32x16_bf16(pa1, v1, o[n], 0, 0, 0);
        }
    }

    __syncthreads();   // last iter's reads done; loop LDS dead

    // Wos slice 0 in flight while we do the epilogue VALU + Os writes
    auto gloadW = [&](int sl) {
#pragma unroll
        for (int p = 0; p < 4; ++p) {
            int chunk = wv * 4 + p;                 // 32 x 1KB chunks
            int S = chunk * 64 + lane;              // 0..2047
            int row = S >> 5, sp = S & 31;
            int ss = sp ^ (row & 7);
            const bf16* g = Wo + (size_t)(sl * 64 + row) * 256 + ss * 8;
            __builtin_amdgcn_global_load_lds((as1_void*)g,
                (as3_void*)(smem + 65536 + chunk * 1024), 16, 0, 0);
        }
    };
    gloadW(0);

    // ---- softmax denominators: lane's lst covers its 16 kv/tile; +partner = all
    lst += __shfl_xor(lst, 32, 64);
    float inv = 1.0f / lst;          // for q = qg*32 + l32
    float invr[16];
#pragma unroll
    for (int r = 0; r < 16; ++r)
        invr[r] = __shfl(inv, (r & 3) + 8 * (r >> 2) + 4 * hi, 64);

    // ---- normalized attended -> Os [128 q][512B], slot s' = s ^ (q&7)
#pragma unroll
    for (int n = 0; n < 4; ++n) {
        int ch = cg * 128 + n * 32 + l32;
        int sl16 = ch >> 3, cb = (ch & 7) * 2;
#pragma unroll
        for (int r = 0; r < 16; ++r) {
            int q = qg * 32 + (r & 3) + 8 * (r >> 2) + 4 * hi;
            *(bf16*)(smem + q * 512 + ((sl16 ^ (q & 7)) << 4) + cb) =
                (bf16)(o[n][r] * invr[r]);
        }
    }
    __syncthreads();   // Os visible; Wos slice 0 drained

    // ---- fused O-projection: 4 slices of 64 out-cols; wave -> 32q x 32out
    const size_t orow0 = (size_t)b * 1024 + qt * 128;
    for (int sl = 0; sl < 4; ++sl) {
        f32x16 acc;
#pragma unroll
        for (int i = 0; i < 16; ++i) acc[i] = 0.0f;
        const int q = qg * 32 + l32;
        const int wr = cg * 32 + l32;
#pragma unroll
        for (int ks = 0; ks < 16; ++ks) {
            int sb = ks * 2 + hi;
            bf16x8 a  = *(const bf16x8*)(smem + q * 512 + ((sb ^ (q & 7)) << 4));
            bf16x8 bb = *(const bf16x8*)(smem + 65536 + wr * 512 + ((sb ^ (wr & 7)) << 4));
            acc = __builtin_amdgcn_mfma_f32_32x32x16_bf16(a, bb, acc, 0, 0, 0);
        }

        int col = sl * 64 + cg * 32 + l32;
        float bvv = bo[col];
#pragma unroll
        for (int r = 0; r < 16; ++r) {
            int qq = qg * 32 + (r & 3) + 8 * (r >> 2) + 4 * hi;
            out[(orow0 + qq) * 256 + col] = acc[r] + bvv;
        }

        if (sl < 3) {
            __syncthreads();     // all waves' Wos reads done
            gloadW(sl + 1);
            __syncthreads();     // next slice drained & visible
        }
    }
}

// ---------------------------------------------------------------------------
extern "C" void kernel_launch(void* const* d_in, const int* in_sizes, int n_in,
                              void* d_out, int out_size, void* d_ws, size_t ws_size,
                              hipStream_t stream)
{
    (void)in_sizes; (void)n_in; (void)out_size; (void)ws_size;
    const float* X  = (const float*)d_in[0];
    const float* Wq = (const float*)d_in[1];
    const float* bq = (const float*)d_in[2];
    const float* Wk = (const float*)d_in[3];
    const float* bk = (const float*)d_in[4];
    const float* Wv = (const float*)d_in[5];
    const float* bv = (const float*)d_in[6];
    const float* Wo = (const float*)d_in[7];
    const float* bo = (const float*)d_in[8];
    float* out = (float*)d_out;

    const size_t NTOK = (size_t)32768 * 256;

    // workspace: Wt (4 mats = 512 KB) + Q + K + Vt
    bf16* Wt  = (bf16*)d_ws;
    bf16* Qw  = (bf16*)d_ws + 262144;
    bf16* Kw  = Qw + NTOK;
    bf16* Vtw = Kw + NTOK;

    transpose_w<<<256, 256, 0, stream>>>(Wq, Wk, Wv, Wo, Wt);
    qkv_gemm   <<<dim3(256, 6), 256, 0, stream>>>(X, Wt, bq, bk, bv, Qw, Kw, Vtw);
    flash_attn <<<dim3(32, 8), 512, 0, stream>>>(Qw, Kw, Vtw, Wt + 3 * 65536, bo, out);
}

// Round 10
// 171.731 us; speedup vs baseline: 1.1334x; 1.0820x over previous
//
#include <hip/hip_runtime.h>
#include <hip/hip_bf16.h>

typedef __bf16 bf16;
typedef __bf16 bf16x2 __attribute__((ext_vector_type(2)));
typedef __bf16 bf16x4 __attribute__((ext_vector_type(4)));
typedef __bf16 bf16x8 __attribute__((ext_vector_type(8)));
typedef float f32x4 __attribute__((ext_vector_type(4)));

// (1/16) * log2(e): softmax scale folded into exp2
#define SM_C 0.09016994374947424f

// ---------------------------------------------------------------------------
// prep: Wq/Wk/Wv/Wo [k][n] f32 -> Wt[mat][n][k] bf16. LDS-tiled 32x32
// transpose. grid 256 = 4 mats x 64 tiles.
// ---------------------------------------------------------------------------
__global__ __launch_bounds__(256) void transpose_w(
    const float* __restrict__ Wq, const float* __restrict__ Wk,
    const float* __restrict__ Wv, const float* __restrict__ Wo,
    bf16* __restrict__ Wt)
{
    __shared__ float T[32][33];
    const int bid = blockIdx.x;
    const int m = bid >> 6, tile = bid & 63;
    const int tn0 = (tile >> 3) * 32, tk0 = (tile & 7) * 32;
    const float* W = (m == 0) ? Wq : (m == 1) ? Wk : (m == 2) ? Wv : Wo;

    const int t = threadIdx.x;
    const int r = t >> 3, c4 = (t & 7) * 4;

    f32x4 v = *(const f32x4*)(W + (size_t)(tk0 + r) * 256 + tn0 + c4);
#pragma unroll
    for (int j = 0; j < 4; ++j) T[r][c4 + j] = v[j];
    __syncthreads();

    bf16x4 ov;
#pragma unroll
    for (int j = 0; j < 4; ++j) ov[j] = (bf16)T[c4 + j][r];
    *(bf16x4*)(Wt + (size_t)m * 65536 + (size_t)(tn0 + r) * 256 + tk0 + c4) = ov;
}

// ---------------------------------------------------------------------------
// Fused QKV as ONE GEMM: C[32768][768] = X[32768][256] x W[256][768].
// grid (256 bm, 6 bn), 256 thr, 128x128 tile, BK=64, 36.9 KB LDS, 3 blk/CU.
// Q/K epilogue via LDS transit (R6, proven -6 us). NEW: V epilogue also via
// LDS transit — old path was 8B stores at 1KB stride (32B segments); now
// staged in Cs2[128 col][136 row-pad] and stored as 256B segments.
// ---------------------------------------------------------------------------
__global__ __launch_bounds__(256, 3) void qkv_gemm(
    const float* __restrict__ X, const bf16* __restrict__ Wt,
    const float* __restrict__ bq, const float* __restrict__ bk,
    const float* __restrict__ bv,
    bf16* __restrict__ Qo, bf16* __restrict__ Ko, bf16* __restrict__ Vto)
{
    __shared__ __align__(16) char qsmem[36864];
    bf16* const Xs  = (bf16*)qsmem;            // [128][72]
    bf16* const Ws_ = (bf16*)(qsmem + 18432);  // [128][72]
    bf16* const Cs  = (bf16*)qsmem;            // Q/K epilogue: [128][132]
    bf16* const Cs2 = (bf16*)qsmem;            // V  epilogue: [128][136]

    const int t    = threadIdx.x;
    const int lane = t & 63, wv = t >> 6;
    const int quad = lane >> 4, l16 = lane & 15;
    const int bm   = blockIdx.x;
    const int bn   = blockIdx.y;
    const int proj = bn >> 1;

    const bf16* W = Wt + (size_t)proj * 65536 + (size_t)(bn & 1) * 32768;
    const float* bias = (proj == 0) ? bq : (proj == 1) ? bk : bv;

    const int m0 = t >> 3;
    const int c0 = (t & 7) * 8;

    const f32x4 zero = {0.0f, 0.0f, 0.0f, 0.0f};
    f32x4 acc[2][8];
#pragma unroll
    for (int i = 0; i < 2; ++i)
#pragma unroll
        for (int j = 0; j < 8; ++j) acc[i][j] = zero;

    f32x4 xa[4], xb[4]; bf16x8 wp[4];
#pragma unroll
    for (int p = 0; p < 4; ++p) {
        const float* px = X + (size_t)(bm * 128 + m0 + p * 32) * 256 + c0;
        xa[p] = *(const f32x4*)px; xb[p] = *(const f32x4*)(px + 4);
        wp[p] = *(const bf16x8*)(W + (size_t)(m0 + p * 32) * 256 + c0);
    }

    for (int kt = 0; kt < 4; ++kt) {
#pragma unroll
        for (int p = 0; p < 4; ++p) {
            bf16x8 r;
#pragma unroll
            for (int j = 0; j < 4; ++j) { r[j] = (bf16)xa[p][j]; r[j + 4] = (bf16)xb[p][j]; }
            *(bf16x8*)(Xs + (m0 + p * 32) * 72 + c0) = r;
            *(bf16x8*)(Ws_ + (m0 + p * 32) * 72 + c0) = wp[p];
        }
        __syncthreads();

        if (kt < 3) {
#pragma unroll
            for (int p = 0; p < 4; ++p) {
                const float* px = X + (size_t)(bm * 128 + m0 + p * 32) * 256 + (kt + 1) * 64 + c0;
                xa[p] = *(const f32x4*)px; xb[p] = *(const f32x4*)(px + 4);
                wp[p] = *(const bf16x8*)(W + (size_t)(m0 + p * 32) * 256 + (kt + 1) * 64 + c0);
            }
        }

#pragma unroll
        for (int ks = 0; ks < 2; ++ks) {
            bf16x8 a[2], bb[8];
#pragma unroll
            for (int mt = 0; mt < 2; ++mt)
                a[mt] = *(const bf16x8*)(Xs + (wv * 32 + mt * 16 + l16) * 72 + ks * 32 + quad * 8);
#pragma unroll
            for (int nt = 0; nt < 8; ++nt)
                bb[nt] = *(const bf16x8*)(Ws_ + (nt * 16 + l16) * 72 + ks * 32 + quad * 8);
#pragma unroll
            for (int mt = 0; mt < 2; ++mt)
#pragma unroll
                for (int nt = 0; nt < 8; ++nt)
                    acc[mt][nt] = __builtin_amdgcn_mfma_f32_16x16x32_bf16(
                        a[mt], bb[nt], acc[mt][nt], 0, 0, 0);
        }
        __syncthreads();
    }

    // epilogue
    if (proj == 2) {
        // V: LDS transit -> coalesced 256B-segment stores into col-major Vt
#pragma unroll
        for (int nt = 0; nt < 8; ++nt) {
            int cl = nt * 16 + l16;               // col-local 0..127
            float bvv = bias[(bn & 1) * 128 + cl];
#pragma unroll
            for (int mt = 0; mt < 2; ++mt) {
                int r0 = wv * 32 + mt * 16 + quad * 4;
                bf16x4 pk;
#pragma unroll
                for (int r = 0; r < 4; ++r) pk[r] = (bf16)(acc[mt][nt][r] + bvv);
                *(bf16x4*)(Cs2 + cl * 136 + r0) = pk;
            }
        }
        __syncthreads();
        const int bq = bm >> 3, moff = (bm & 7) * 128;
#pragma unroll
        for (int i = 0; i < 8; ++i) {
            int chunk = i * 256 + t;
            int cl = chunk >> 4, rp = (chunk & 15) * 8;
            bf16x8 v = *(const bf16x8*)(Cs2 + cl * 136 + rp);
            *(bf16x8*)(Vto + (size_t)bq * 262144 +
                       (size_t)((bn & 1) * 128 + cl) * 1024 + moff + rp) = v;
        }
    } else {
        bf16* dst = (proj == 0) ? Qo : Ko;
#pragma unroll
        for (int nt = 0; nt < 8; ++nt) {
            float bvv = bias[(bn & 1) * 128 + nt * 16 + l16];
#pragma unroll
            for (int mt = 0; mt < 2; ++mt)
#pragma unroll
                for (int r = 0; r < 4; ++r)
                    Cs[(wv * 32 + mt * 16 + quad * 4 + r) * 132 + nt * 16 + l16] =
                        (bf16)(acc[mt][nt][r] + bvv);
        }
        __syncthreads();
#pragma unroll
        for (int i = 0; i < 8; ++i) {
            int chunk = i * 256 + t;
            int row = chunk >> 4, cc = chunk & 15;
            bf16x8 v = *(const bf16x8*)(Cs + row * 132 + cc * 8);
            *(bf16x8*)(dst + (size_t)(bm * 128 + row) * 256 + (bn & 1) * 128 + cc * 8) = v;
        }
    }
}

// ---------------------------------------------------------------------------
// Flash attention + fused O-projection (R4 structure + swapped-QK packed-P).
// 512 thr / 8 waves, grid (32 b, 8 qt), 16 q-rows/wave (occupancy-forced:
// 32768 q-rows / 2048 waves needed for 2 waves/SIMD). Double-buffered K/V,
// one barrier per KV tile, register prefetch.
// CHANGE vs R4: QK^T computed swapped — mfma(K, Q): identical LDS addresses
// and register layouts (A and B share the [idx=l16][k=quad*8+j] lane map),
// but D becomes [row=kv][col=q], so each lane owns P values in its OWN
// P-row (q=l16) -> P written as 4 packed b32 (one lane per dword) instead
// of 16 scalar b16 (two lanes per dword = serialized RMW; that was the
// 10.5M-cycle SQ_LDS_BANK_CONFLICT source — R7 measured 6.0M with this
// scheme). af read and PV are unchanged.
// Epilogue: fused O-projection (R4 verbatim; only the lst reduction axis
// changes: quad-shfl instead of l16-shfl, R7-verified indexing).
// ---------------------------------------------------------------------------
__global__ __launch_bounds__(512, 2) void flash_attn(
    const bf16* __restrict__ Qr, const bf16* __restrict__ K,
    const bf16* __restrict__ Vt, const bf16* __restrict__ Wo,
    const float* __restrict__ bo, float* __restrict__ out)
{
    __shared__ __align__(16) char smem[142336];
    bf16* const Ksp0 = (bf16*)(smem);
    bf16* const Ksp1 = (bf16*)(smem + 16896);
    bf16* const Vsp0 = (bf16*)(smem + 33792);
    bf16* const Vsp1 = (bf16*)(smem + 54272);
    bf16* const Os   = (bf16*)(smem);
    bf16* const Wos  = (bf16*)(smem + 74752);

    const int t    = threadIdx.x;
    const int lane = t & 63, wv = t >> 6;          // wv 0..7
    const int quad = lane >> 4, l16 = lane & 15;
    const int b  = blockIdx.x;   // 0..31  (fastest -> XCD = b % 8)
    const int qt = blockIdx.y;   // 0..7

    char* const Pb = smem + 74752 + wv * 1024;     // per-wave P [16 q][64B kv]
    const int psw = (l16 & 7) << 4;

    // Q fragments (B operand of swapped QK^T; same registers as R4's A use)
    bf16x8 qf[8];
    const size_t qrow = (size_t)b * 1024 + qt * 128 + wv * 16 + l16;
#pragma unroll
    for (int ks = 0; ks < 8; ++ks)
        qf[ks] = *(const bf16x8*)(Qr + qrow * 256 + ks * 32 + quad * 8);

    const f32x4 zero = {0.0f, 0.0f, 0.0f, 0.0f};
    f32x4 o[16];
#pragma unroll
    for (int n = 0; n < 16; ++n) o[n] = zero;
    float lst = 0.f;

    // staging index split (512 threads, 2 x 16B each for K and V)
    const int kv0 = t >> 4, kc0 = (t & 15) * 8;   // K: row kv0, elems kc0 + p*128
    const int vc0 = t >> 1, vm0 = (t & 1) * 8;    // V: row vc0, elems vm0 + p*16

    bf16x8 kp[2], vp[2];
    // prologue: tile 0 -> buf 0; tile 1 loads in flight
#pragma unroll
    for (int p = 0; p < 2; ++p) {
        kp[p] = *(const bf16x8*)(K + (size_t)(b * 1024 + kv0) * 256 + kc0 + p * 128);
        vp[p] = *(const bf16x8*)(Vt + (size_t)b * 262144 + (size_t)vc0 * 1024 + vm0 + p * 16);
    }
#pragma unroll
    for (int p = 0; p < 2; ++p) {
        *(bf16x8*)(Ksp0 + kv0 * 264 + kc0 + p * 128) = kp[p];
        *(bf16x8*)(Vsp0 + vc0 * 40 + vm0 + p * 16) = vp[p];
    }
#pragma unroll
    for (int p = 0; p < 2; ++p) {
        kp[p] = *(const bf16x8*)(K + (size_t)(b * 1024 + 32 + kv0) * 256 + kc0 + p * 128);
        vp[p] = *(const bf16x8*)(Vt + (size_t)b * 262144 + (size_t)vc0 * 1024 + 32 + vm0 + p * 16);
    }

    for (int j = 0; j < 32; ++j) {
        const bf16* Kb = (j & 1) ? Ksp1 : Ksp0;
        const bf16* Vb = (j & 1) ? Vsp1 : Vsp0;
        __syncthreads();   // tile j stores visible; prior reads of buf^1 done

        // ---- swapped S = K Q^T : D[row=kv (kvt*16+quad*4+r)][col=q (l16)]
        f32x4 s[2];
        s[0] = zero; s[1] = zero;
#pragma unroll
        for (int ks = 0; ks < 8; ++ks) {
#pragma unroll
            for (int kvt = 0; kvt < 2; ++kvt) {
                bf16x8 kb = *(const bf16x8*)(Kb + (kvt * 16 + l16) * 264 + ks * 32 + quad * 8);
                s[kvt] = __builtin_amdgcn_mfma_f32_16x16x32_bf16(kb, qf[ks], s[kvt], 0, 0, 0);
            }
        }

        // ---- commit tile j+1 into other buffer; issue tile j+2 loads
        if (j < 31) {
            bf16* Kn = (j & 1) ? Ksp0 : Ksp1;
            bf16* Vn = (j & 1) ? Vsp0 : Vsp1;
#pragma unroll
            for (int p = 0; p < 2; ++p) {
                *(bf16x8*)(Kn + kv0 * 264 + kc0 + p * 128) = kp[p];
                *(bf16x8*)(Vn + vc0 * 40 + vm0 + p * 16) = vp[p];
            }
            if (j < 30) {
#pragma unroll
                for (int p = 0; p < 2; ++p) {
                    kp[p] = *(const bf16x8*)(K + (size_t)(b * 1024 + (j + 2) * 32 + kv0) * 256 + kc0 + p * 128);
                    vp[p] = *(const bf16x8*)(Vt + (size_t)b * 262144 + (size_t)vc0 * 1024 + (j + 2) * 32 + vm0 + p * 16);
                }
            }
        }

        // ---- no-max softmax; packed P: lane writes its OWN row q=l16,
        //      kv = kvt*16 + quad*4 + {0..3} -> two b32 per kvt
#pragma unroll
        for (int kvt = 0; kvt < 2; ++kvt) {
#pragma unroll
            for (int h = 0; h < 2; ++h) {
                float p0 = __builtin_amdgcn_exp2f(s[kvt][2 * h] * SM_C);
                float p1 = __builtin_amdgcn_exp2f(s[kvt][2 * h + 1] * SM_C);
                lst += p0 + p1;
                bf16x2 pk; pk[0] = (bf16)p0; pk[1] = (bf16)p1;
                *(bf16x2*)(Pb + ((l16 * 64 + kvt * 32 + quad * 8 + h * 4) ^ psw)) = pk;
            }
        }

        // ---- O += P V  (af read and PV unchanged from R4)
        bf16x8 af = *(const bf16x8*)(Pb + ((l16 * 64 + quad * 16) ^ psw));
#pragma unroll
        for (int n = 0; n < 16; ++n) {
            bf16x8 bfr = *(const bf16x8*)(Vb + (n * 16 + l16) * 40 + quad * 8);
            o[n] = __builtin_amdgcn_mfma_f32_16x16x32_bf16(af, bfr, o[n], 0, 0, 0);
        }
    }

    __syncthreads();   // all PV reads of Ks/Vs done before Os overwrites them

    // ---- softmax denominators: lane's lst covers q=l16, kv slots of its
    //      quad -> reduce across quad (xor 16, 32); then broadcast per r
    lst += __shfl_xor(lst, 16, 64);
    lst += __shfl_xor(lst, 32, 64);
    float inv[4];
#pragma unroll
    for (int r = 0; r < 4; ++r)
        inv[r] = 1.0f / __shfl(lst, quad * 4 + r, 64);

#pragma unroll
    for (int n = 0; n < 16; ++n)
#pragma unroll
        for (int r = 0; r < 4; ++r)
            Os[(wv * 16 + quad * 4 + r) * 264 + n * 16 + l16] = (bf16)(o[n][r] * inv[r]);

    // ---- fused O-projection: out[128][256] = Os x Wo^T(+bo), two col-halves
    const int rh = (wv & 1) * 64;      // wave's row strip
    const int nq = wv >> 1;            // wave's 32-col strip within half
    const size_t orow0 = (size_t)b * 1024 + qt * 128 + rh;

#pragma unroll
    for (int h = 0; h < 2; ++h) {
        if (h) __syncthreads();        // previous half's Wos reads done
        // stage Wo half h: rows h*128..h*128+127 of Wo[n][k]
#pragma unroll
        for (int i = 0; i < 8; ++i) {
            int c = t + i * 512;
            int row = c >> 5, c8 = (c & 31) * 8;
            *(bf16x8*)(Wos + row * 264 + c8) =
                *(const bf16x8*)(Wo + (size_t)(h * 128 + row) * 256 + c8);
        }
        __syncthreads();               // Os (h==0) + Wos half visible

        f32x4 acc[4][2];
#pragma unroll
        for (int mt = 0; mt < 4; ++mt) { acc[mt][0] = zero; acc[mt][1] = zero; }

#pragma unroll
        for (int ks = 0; ks < 8; ++ks) {
            bf16x8 a[4], bb[2];
#pragma unroll
            for (int mt = 0; mt < 4; ++mt)
                a[mt] = *(const bf16x8*)(Os + (rh + mt * 16 + l16) * 264 + ks * 32 + quad * 8);
#pragma unroll
            for (int nt = 0; nt < 2; ++nt)
                bb[nt] = *(const bf16x8*)(Wos + (nq * 32 + nt * 16 + l16) * 264 + ks * 32 + quad * 8);
#pragma unroll
            for (int mt = 0; mt < 4; ++mt)
#pragma unroll
                for (int nt = 0; nt < 2; ++nt)
                    acc[mt][nt] = __builtin_amdgcn_mfma_f32_16x16x32_bf16(
                        a[mt], bb[nt], acc[mt][nt], 0, 0, 0);
        }

#pragma unroll
        for (int nt = 0; nt < 2; ++nt) {
            int col = h * 128 + nq * 32 + nt * 16 + l16;
            float bvv = bo[col];
#pragma unroll
            for (int mt = 0; mt < 4; ++mt) {
#pragma unroll
                for (int r = 0; r < 4; ++r) {
                    size_t row = orow0 + mt * 16 + quad * 4 + r;
                    out[row * 256 + col] = acc[mt][nt][r] + bvv;
                }
            }
        }
    }
}

// ---------------------------------------------------------------------------
extern "C" void kernel_launch(void* const* d_in, const int* in_sizes, int n_in,
                              void* d_out, int out_size, void* d_ws, size_t ws_size,
                              hipStream_t stream)
{
    (void)in_sizes; (void)n_in; (void)out_size; (void)ws_size;
    const float* X  = (const float*)d_in[0];
    const float* Wq = (const float*)d_in[1];
    const float* bq = (const float*)d_in[2];
    const float* Wk = (const float*)d_in[3];
    const float* bk = (const float*)d_in[4];
    const float* Wv = (const float*)d_in[5];
    const float* bv = (const float*)d_in[6];
    const float* Wo = (const float*)d_in[7];
    const float* bo = (const float*)d_in[8];
    float* out = (float*)d_out;

    const size_t NTOK = (size_t)32768 * 256;

    // workspace: Wt (4 mats = 512 KB) + Q + K + Vt
    bf16* Wt  = (bf16*)d_ws;
    bf16* Qw  = (bf16*)d_ws + 262144;
    bf16* Kw  = Qw + NTOK;
    bf16* Vtw = Kw + NTOK;

    transpose_w<<<256, 256, 0, stream>>>(Wq, Wk, Wv, Wo, Wt);
    qkv_gemm   <<<dim3(256, 6), 256, 0, stream>>>(X, Wt, bq, bk, bv, Qw, Kw, Vtw);
    flash_attn <<<dim3(32, 8), 512, 0, stream>>>(Qw, Kw, Vtw, Wt + 3 * 65536, bo, out);
}